// Round 9
// baseline (335.615 us; speedup 1.0000x reference)
//
#include <hip/hip_runtime.h>
#include <hip/hip_bf16.h>

// ---------------------------------------------------------------------------
// attention via: E = exp(QK^T/32) (bf16), inv[r] = 1/sum_k E[r,k] (per-wave
// partials), O = diag(inv)*E*V.
// Both GEMMs: BK=32, 4-buffer LDS ring, DEEP counted-vmcnt pipeline:
//   tile t: ph0 {stage A(t+3); ds a(mh0)+b; BAR; MFMA mh0; BAR}
//           ph1 {stage B(t+3); ds a(mh1); BAR; MFMA mh1; VM(2*LPT); BAR}
//   VM(2*LPT) forces only tile t+1 landed (staged at t-2, ~2-tile lead ->
//   covers HBM); t+2,t+3 stay in flight. Never drains mid-loop.
// LDS: rows r and r+BM/2 share one 128B row; slot = (chunk+4*half)^(row&7)
// (full-XOR, measured-0-conflict family). Staged via inverse-bijection global
// source + linear LDS dest (rule #21). Relaxed barriers (compiler lgkm).
// T1 decode: GEMM1 supertile 16x8/XCD (FETCH 96MB verified); GEMM2 bm-fastest.
// ws: [0,128MB)=E ; [128MB,144MB)=V^T ; [144MB,148MB)=partials ; then inv.
// ---------------------------------------------------------------------------

typedef __bf16 bf16x8 __attribute__((ext_vector_type(8)));
typedef float f32x4 __attribute__((ext_vector_type(4)));
typedef const __attribute__((address_space(1))) unsigned int* as1p;
typedef __attribute__((address_space(3))) unsigned int* as3p;
typedef unsigned short u16;

__device__ __forceinline__ u16 f2bf(float x) {
  unsigned u = __float_as_uint(x);
  u += 0x7fffu + ((u >> 16) & 1u);
  return (u16)(u >> 16);
}
__device__ __forceinline__ float bf2f(u16 b) { return __uint_as_float(((unsigned)b) << 16); }
__device__ __forceinline__ unsigned pack2(float lo, float hi) {
  return (unsigned)f2bf(lo) | ((unsigned)f2bf(hi) << 16);
}

#define BAR()   do { __builtin_amdgcn_s_barrier(); asm volatile("" ::: "memory"); } while (0)
#define VM(n)   do { asm volatile("s_waitcnt vmcnt(" #n ")" ::: "memory"); __builtin_amdgcn_sched_barrier(0); } while (0)

// --------------------------- f32 -> bf16 convert ---------------------------
__global__ __launch_bounds__(256) void cvt_bf16(const float* __restrict__ in,
                                                unsigned short* __restrict__ out) {
  const size_t i = (size_t)blockIdx.x * 256 + threadIdx.x;
  const float4* p = (const float4*)in + i * 2;
  float4 a = p[0], b = p[1];
  uint4 o;
  o.x = pack2(a.x, a.y);
  o.y = pack2(a.z, a.w);
  o.z = pack2(b.x, b.y);
  o.w = pack2(b.z, b.w);
  ((uint4*)out)[i] = o;
}

// ------------- V [8192,1024] f32 -> V^T [1024,8192] bf16 -------------------
__global__ __launch_bounds__(256) void transpose_bf16(const float* __restrict__ V,
                                                      unsigned short* __restrict__ VT) {
  __shared__ float t[64][65];
  const int rb = blockIdx.x * 64;
  const int cb = blockIdx.y * 64;
  const int tid = threadIdx.x;
#pragma unroll
  for (int it = 0; it < 4; ++it) {
    int r = it * 16 + (tid >> 4);
    int c = (tid & 15) * 4;
    float4 x = *(const float4*)(V + (size_t)(rb + r) * 1024 + cb + c);
    t[r][c] = x.x; t[r][c + 1] = x.y; t[r][c + 2] = x.z; t[r][c + 3] = x.w;
  }
  __syncthreads();
  const int j = tid & 63;
  const int c0 = (tid >> 6) * 16;
#pragma unroll
  for (int i = 0; i < 16; ++i) {
    int c = c0 + i;
    VT[(size_t)(cb + c) * 8192 + rb + j] = f2bf(t[j][c]);
  }
}

// ------------------ deep-pipe NT GEMM (BK=32, 4-buf ring) ------------------
// C[M,N](ldc) = A[M,K]*B[N,K]^T, BN=256. 512 threads, 8 waves (2M x 4N).
// DEC 0: grid 1024 = supertile 16bm x 8bn per XCD chunk   [GEMM1]
// DEC 1: grid 256  = bm-fastest, VT quadrant L2-resident  [GEMM2]
// OUTMODE 0: C=bf16 exp(acc*scale) + per-wave row partials.
// OUTMODE 1: C=f32 acc*inv[row].
template <int BM, int OUTMODE, int DEC>
__global__ __launch_bounds__(512, 2) void gemm_dp(const u16* __restrict__ A,
                                                  const u16* __restrict__ B,
                                                  void* __restrict__ Cv,
                                                  const float* __restrict__ inv,
                                                  float* __restrict__ partials,
                                                  int K, int ldc, float scale) {
  constexpr int MF = BM / 32;       // per-wave m-frags (8 or 4)
  constexpr int MH = MF / 2;
  constexpr int LA = BM / 128;      // A gloads/thread/tile (2 or 1)
  constexpr int LPT = LA + 2;       // loads/thread/tile (4 or 3)
  constexpr int ABUFB = BM * 64;    // A bytes/buffer (16K or 8K)
  constexpr int BUFSZ = ABUFB + 16384;  // + B 256x32x2B
  __shared__ __align__(1024) char smem[4 * BUFSZ];

  const int tid = threadIdx.x;
  const int lane = tid & 63, wave = tid >> 6;
  const int wr = wave >> 2, wc = wave & 3;
  const int lan15 = lane & 15, g = lane >> 4, l7 = lane & 7;

  // T1: bijective XCD swizzle (nwg % 8 == 0 at both call sites)
  const int nwg = gridDim.x;
  const int wg = (blockIdx.x & 7) * (nwg >> 3) + (blockIdx.x >> 3);
  int bm0, bn0;
  if constexpr (DEC == 0) {
    const int r = wg & 255;
    bm0 = (r >> 3) * 256;
    bn0 = (((wg >> 8) << 3) | (r & 7)) * 256;
  } else {
    bm0 = (wg & 63) * BM;
    bn0 = (wg >> 6) * 256;
  }

  // ---- staging bijection: thread -> (ldsrow rho, slot s) -> (row, chunk).
  // LDS row rho holds global rows {rho, rho+HP} x 4 chunks; slot s holds
  // (chunk c, half h) with c+4h = s ^ (rho&7).  HP = BM/2 (A), 128 (B).
  const int rho = tid >> 3;          // 0..63 per load batch
  const int s8 = tid & 7;
  const int xx = s8 ^ (rho & 7);     // (j*64) & 7 == 0, so same for all j
  const int cc = xx & 3, hh = xx >> 2;

  const u16* AgJ[LA];
#pragma unroll
  for (int j = 0; j < LA; ++j) {
    const int rA = j * 64 + rho + (BM / 2) * hh;
    AgJ[j] = A + (size_t)(bm0 + rA) * K + cc * 8;
  }
  const u16* BgJ[2];
#pragma unroll
  for (int j = 0; j < 2; ++j) {
    const int rB = j * 64 + rho + 128 * hh;
    BgJ[j] = B + (size_t)(bn0 + rB) * K + cc * 8;
  }

  // ---- fragment-read offsets (within buffer), slot XOR by (g + 4*half)
  const int saA = ((g + 4 * wr) ^ l7) * 16;
  const int saB = ((g + 4 * (wc >> 1)) ^ l7) * 16;
  const int brow = ABUFB + ((wc & 1) * 64 + lan15) * 128 + saB;  // + n*2048
  const int arow = lan15 * 128 + saA;                            // + mf*2048

  f32x4 acc[MF][4];
#pragma unroll
  for (int m = 0; m < MF; ++m)
#pragma unroll
    for (int n = 0; n < 4; ++n) acc[m][n] = f32x4{0.f, 0.f, 0.f, 0.f};

  const int nt = K >> 5;  // BK=32 tiles

  auto ISSUE_A = [&](int t) {
    char* bb = smem + (t & 3) * BUFSZ;
#pragma unroll
    for (int j = 0; j < LA; ++j)
      __builtin_amdgcn_global_load_lds((as1p)(AgJ[j] + t * 32),
                                       (as3p)(bb + j * 8192 + tid * 16), 16, 0, 0);
  };
  auto ISSUE_B = [&](int t) {
    char* bb = smem + (t & 3) * BUFSZ + ABUFB;
#pragma unroll
    for (int j = 0; j < 2; ++j)
      __builtin_amdgcn_global_load_lds((as1p)(BgJ[j] + t * 32),
                                       (as3p)(bb + j * 8192 + tid * 16), 16, 0, 0);
  };

  // prologue: stage tiles 0,1,2 ; force tile 0 landed (1,2 stay in flight)
  ISSUE_A(0); ISSUE_B(0);
  ISSUE_A(1); ISSUE_B(1);
  ISSUE_A(2); ISSUE_B(2);
  if constexpr (LPT == 4) { VM(8); } else { VM(6); }
  BAR();

  bf16x8 a[MH], b[4];
  for (int t = 0; t < nt; ++t) {
    const char* bp = smem + (t & 3) * BUFSZ;
    const bool st = (t + 3 < nt);

    // ---- ph0: stage A(t+3); ds a(mh0) + b(all); MFMA mh0 -----------------
    if (st) ISSUE_A(t + 3);
#pragma unroll
    for (int m = 0; m < MH; ++m) a[m] = *(const bf16x8*)(bp + arow + m * 2048);
#pragma unroll
    for (int n = 0; n < 4; ++n) b[n] = *(const bf16x8*)(bp + brow + n * 2048);
    BAR();
    __builtin_amdgcn_s_setprio(1);
#pragma unroll
    for (int m = 0; m < MH; ++m)
#pragma unroll
      for (int n = 0; n < 4; ++n)
        acc[m][n] = __builtin_amdgcn_mfma_f32_16x16x32_bf16(a[m], b[n], acc[m][n], 0, 0, 0);
    __builtin_amdgcn_s_setprio(0);
    BAR();

    // ---- ph1: stage B(t+3); ds a(mh1); MFMA mh1; counted wait ------------
    if (st) ISSUE_B(t + 3);
#pragma unroll
    for (int m = 0; m < MH; ++m) a[m] = *(const bf16x8*)(bp + arow + (MH + m) * 2048);
    BAR();
    __builtin_amdgcn_s_setprio(1);
#pragma unroll
    for (int m = 0; m < MH; ++m)
#pragma unroll
      for (int n = 0; n < 4; ++n)
        acc[MH + m][n] = __builtin_amdgcn_mfma_f32_16x16x32_bf16(a[m], b[n], acc[MH + m][n], 0, 0, 0);
    __builtin_amdgcn_s_setprio(0);
    // force tile t+1 landed; keep t+2 (and t+3 if staged) in flight
    if (st) {
      if constexpr (LPT == 4) { VM(8); } else { VM(6); }
    } else if (t + 2 < nt) {
      if constexpr (LPT == 4) { VM(4); } else { VM(3); }
    } else if (t + 1 < nt) {
      VM(0);
    }
    BAR();
  }

  // ---- epilogue. C/D map: col = lane&15, row = (lane>>4)*4 + reg
  const int c0 = bn0 + wc * 64 + lan15;
  if constexpr (OUTMODE == 0) {
    u16* C = (u16*)Cv;
    const int cb4 = (bn0 >> 8) * 4 + wc;  // partial-column index (0..127)
#pragma unroll
    for (int m = 0; m < MF; ++m)
#pragma unroll
      for (int r = 0; r < 4; ++r) {
        const int row = bm0 + wr * (BM / 2) + m * 16 + g * 4 + r;
        float part = 0.f;
#pragma unroll
        for (int n = 0; n < 4; ++n) {
          float v = __expf(acc[m][n][r] * scale);
          C[(size_t)row * ldc + c0 + n * 16] = f2bf(v);
          part += v;
        }
        part += __shfl_xor(part, 1, 64);
        part += __shfl_xor(part, 2, 64);
        part += __shfl_xor(part, 4, 64);
        part += __shfl_xor(part, 8, 64);
        if (lan15 == 0) partials[(size_t)row * 128 + cb4] = part;
      }
  } else {
    float* C = (float*)Cv;
#pragma unroll
    for (int m = 0; m < MF; ++m)
#pragma unroll
      for (int r = 0; r < 4; ++r) {
        const int row = bm0 + wr * (BM / 2) + m * 16 + g * 4 + r;
        const float iv = inv ? inv[row] : 1.0f;
#pragma unroll
        for (int n = 0; n < 4; ++n)
          C[(size_t)row * ldc + c0 + n * 16] = acc[m][n][r] * iv;
      }
  }
}

// ---------------- inv[row] = 1 / sum_j partials[row][j] --------------------
__global__ __launch_bounds__(256) void rowinv(const float* __restrict__ partials,
                                              float* __restrict__ inv) {
  const int row = blockIdx.x * 256 + threadIdx.x;
  const float4* p = (const float4*)(partials + (size_t)row * 128);
  float s = 0.f;
#pragma unroll
  for (int j = 0; j < 32; ++j) {
    float4 v = p[j];
    s += (v.x + v.y) + (v.z + v.w);
  }
  inv[row] = 1.0f / s;
}

// --------------- fallback: normalize E rows in place (bf16) ----------------
__global__ __launch_bounds__(256) void normalize_inplace(u16* __restrict__ E) {
  __shared__ float red[4];
  u16* row = E + (size_t)blockIdx.x * 8192;
  const int tid = threadIdx.x;
  float f[32];
  float s = 0.f;
#pragma unroll
  for (int c = 0; c < 4; ++c) {
    uint4 v = *((const uint4*)row + c * 256 + tid);
    unsigned u[4] = {v.x, v.y, v.z, v.w};
#pragma unroll
    for (int q = 0; q < 4; ++q) {
      f[c * 8 + q * 2] = bf2f((u16)(u[q] & 0xffffu));
      f[c * 8 + q * 2 + 1] = bf2f((u16)(u[q] >> 16));
      s += f[c * 8 + q * 2] + f[c * 8 + q * 2 + 1];
    }
  }
#pragma unroll
  for (int off = 32; off; off >>= 1) s += __shfl_xor(s, off, 64);
  if ((tid & 63) == 0) red[tid >> 6] = s;
  __syncthreads();
  const float iv = 1.0f / ((red[0] + red[1]) + (red[2] + red[3]));
#pragma unroll
  for (int c = 0; c < 4; ++c) {
    uint4 o;
    o.x = pack2(f[c * 8 + 0] * iv, f[c * 8 + 1] * iv);
    o.y = pack2(f[c * 8 + 2] * iv, f[c * 8 + 3] * iv);
    o.z = pack2(f[c * 8 + 4] * iv, f[c * 8 + 5] * iv);
    o.w = pack2(f[c * 8 + 6] * iv, f[c * 8 + 7] * iv);
    *((uint4*)row + c * 256 + tid) = o;
  }
}

// ---------------------------------------------------------------------------
extern "C" void kernel_launch(void* const* d_in, const int* in_sizes, int n_in,
                              void* d_out, int out_size, void* d_ws, size_t ws_size,
                              hipStream_t stream) {
  const float* Q = (const float*)d_in[0];
  const float* K = (const float*)d_in[1];
  const float* V = (const float*)d_in[2];

  char* ws = (char*)d_ws;
  u16* S = (u16*)ws;                                              // 128 MB
  u16* VT = (u16*)(ws + (size_t)134217728);                       // 16 MB
  float* partials = (float*)(ws + (size_t)134217728 + 16777216);  // 4 MB
  float* inv = (float*)(ws + (size_t)134217728 + 16777216 + 4194304);
  const bool haveInv =
      ws_size >= (size_t)134217728 + 16777216 + 4194304 + 32768;

  u16* Qb = (u16*)d_out;   // bf16 Q scratch (16 MB)
  u16* Kb = Qb + 8388608;  // bf16 K scratch (16 MB)

  cvt_bf16<<<4096, 256, 0, stream>>>(Q, Qb);
  cvt_bf16<<<4096, 256, 0, stream>>>(K, Kb);
  transpose_bf16<<<dim3(128, 16), 256, 0, stream>>>(V, VT);

  // E = exp(Q K^T / 32)  [8192 x 8192] bf16 ; grid 1024
  gemm_dp<256, 0, 0><<<1024, 512, 0, stream>>>(
      Qb, Kb, S, nullptr, haveInv ? partials : (float*)(ws + 134217728 + 16777216),
      1024, 8192, 1.0f / 32.0f);

  if (haveInv) {
    rowinv<<<32, 256, 0, stream>>>(partials, inv);
    // O = diag(inv) E V  [8192 x 1024] f32 ; grid 256
    gemm_dp<128, 1, 1><<<256, 512, 0, stream>>>(
        S, VT, d_out, inv, nullptr, 8192, 1024, 1.0f);
  } else {
    normalize_inplace<<<8192, 256, 0, stream>>>(S);
    gemm_dp<128, 1, 1><<<256, 512, 0, stream>>>(
        S, VT, d_out, nullptr, nullptr, 8192, 1024, 1.0f);
  }
}

// Round 10
// 334.881 us; speedup vs baseline: 1.0022x; 1.0022x over previous
//
#include <hip/hip_runtime.h>
#include <hip/hip_bf16.h>

// ---------------------------------------------------------------------------
// attention via: E = exp(QK^T/32) (bf16), inv[r] = 1/sum_k E[r,k] (per-wave
// partials), O = diag(inv)*E*V.
// KEY CHANGE (r10): K and V are pre-packed into MFMA B-FRAGMENT layout
// ([nb][kt][ks][lane][8 bf16]), so both GEMMs load B operands DIRECTLY from
// global/L2 into registers (coalesced 1KB dwordx4 per frag, double-buffered
// 1 tile ahead) — zero LDS traffic for B. LDS holds only A (the 4x-shared
// operand): GEMM1 LDS/tile 256->160 KB, GEMM2 176->80 KB. ONE barrier per
// K-tile (LGKM0 + counted VM(8) + BAR guards A-buffer retire/landing).
// T1 decodes kept (GEMM1 supertile 16x8/XCD, FETCH 96MB verified; GEMM2
// bm-fastest VT-quadrant-resident). A-path swizzle unchanged (0 conflicts).
// ws: [0,128MB)=E ; [128MB,144MB)=Vfrag ; [144MB,148MB)=partials ; then inv.
// d_out: [0,16MB)=Qb row-major bf16, [16,32MB)=Kfrag — dead once GEMM2 runs.
// ---------------------------------------------------------------------------

typedef __bf16 bf16x8 __attribute__((ext_vector_type(8)));
typedef float f32x4 __attribute__((ext_vector_type(4)));
typedef const __attribute__((address_space(1))) unsigned int* as1p;
typedef __attribute__((address_space(3))) unsigned int* as3p;
typedef unsigned short u16;

__device__ __forceinline__ u16 f2bf(float x) {
  unsigned u = __float_as_uint(x);
  u += 0x7fffu + ((u >> 16) & 1u);
  return (u16)(u >> 16);
}
__device__ __forceinline__ float bf2f(u16 b) { return __uint_as_float(((unsigned)b) << 16); }
__device__ __forceinline__ unsigned pack2(float lo, float hi) {
  return (unsigned)f2bf(lo) | ((unsigned)f2bf(hi) << 16);
}

#define BAR()   do { __builtin_amdgcn_s_barrier(); asm volatile("" ::: "memory"); } while (0)
#define SCHED0() __builtin_amdgcn_sched_barrier(0)
#define LGKM0() do { asm volatile("s_waitcnt lgkmcnt(0)" ::: "memory"); __builtin_amdgcn_sched_barrier(0); } while (0)
#define VM(n)   do { asm volatile("s_waitcnt vmcnt(" #n ")" ::: "memory"); __builtin_amdgcn_sched_barrier(0); } while (0)

// --------------------------- Q: f32 -> bf16 row-major ----------------------
__global__ __launch_bounds__(256) void cvt_bf16(const float* __restrict__ in,
                                                unsigned short* __restrict__ out) {
  const size_t i = (size_t)blockIdx.x * 256 + threadIdx.x;
  const float4* p = (const float4*)in + i * 2;
  float4 a = p[0], b = p[1];
  uint4 o;
  o.x = pack2(a.x, a.y);
  o.y = pack2(a.z, a.w);
  o.z = pack2(b.x, b.y);
  o.w = pack2(b.z, b.w);
  ((uint4*)out)[i] = o;
}

// ------------- K [8192 n][1024 k] f32 -> B-frag layout bf16 ----------------
// frag elem (nb,kt,ks,lane,j): n = nb*16+(lane&15), k = kt*64+ks*32+(lane>>4)*8+j
// addr (uint4 units) = ((nb*16 + kt)*2 + ks)*64 + lane ; nb 0..511, kt 0..15
__global__ __launch_bounds__(256) void kfrag_write(const float* __restrict__ K,
                                                   uint4* __restrict__ Kf) {
  __shared__ float lds[16][257];
  const int nb = blockIdx.x;    // 0..511
  const int ktg = blockIdx.y;   // 0..3 (4 kt each)
  const int tid = threadIdx.x;
#pragma unroll
  for (int p = 0; p < 4; ++p) {
    const int row = p * 4 + (tid >> 6);
    const int c = (tid & 63) * 4;
    float4 v = *(const float4*)(K + (size_t)(nb * 16 + row) * 1024 + ktg * 256 + c);
    lds[row][c] = v.x; lds[row][c + 1] = v.y; lds[row][c + 2] = v.z; lds[row][c + 3] = v.w;
  }
  __syncthreads();
#pragma unroll
  for (int w = 0; w < 2; ++w) {
    const int o = w * 256 + tid;
    const int kt_loc = o >> 7, ks = (o >> 6) & 1, lane = o & 63;
    const int nl = lane & 15;
    const int kb = kt_loc * 64 + ks * 32 + ((lane >> 4) & 3) * 8;
    uint4 q;
    q.x = pack2(lds[nl][kb + 0], lds[nl][kb + 1]);
    q.y = pack2(lds[nl][kb + 2], lds[nl][kb + 3]);
    q.z = pack2(lds[nl][kb + 4], lds[nl][kb + 5]);
    q.w = pack2(lds[nl][kb + 6], lds[nl][kb + 7]);
    Kf[(((size_t)nb * 16 + ktg * 4 + kt_loc) * 2 + ks) * 64 + lane] = q;
  }
}

// ------------- V [8192 kv][1024 col] f32 -> B-frag layout (V^T) ------------
// frag elem (nb,kt,ks,lane,j): col = nb*16+(lane&15), kv = kt*64+ks*32+(lane>>4)*8+j
// addr (uint4) = ((nb*128 + kt)*2 + ks)*64 + lane ; nb 0..63, kt 0..127
__global__ __launch_bounds__(256) void vfrag_write(const float* __restrict__ V,
                                                   uint4* __restrict__ Vf) {
  __shared__ float lds[256][17];
  const int nb = blockIdx.x;    // 0..63  (col group)
  const int ktg = blockIdx.y;   // 0..31  (4 kt each = 256 kv)
  const int tid = threadIdx.x;
#pragma unroll
  for (int p = 0; p < 4; ++p) {
    const int row = p * 64 + (tid >> 2);
    const int cf = (tid & 3) * 4;
    float4 v = *(const float4*)(V + (size_t)(ktg * 256 + row) * 1024 + nb * 16 + cf);
    lds[row][cf] = v.x; lds[row][cf + 1] = v.y; lds[row][cf + 2] = v.z; lds[row][cf + 3] = v.w;
  }
  __syncthreads();
#pragma unroll
  for (int w = 0; w < 2; ++w) {
    const int o = w * 256 + tid;
    const int kt_loc = o >> 7, ks = (o >> 6) & 1, lane = o & 63;
    const int cl = lane & 15;
    const int kvb = kt_loc * 64 + ks * 32 + ((lane >> 4) & 3) * 8;
    uint4 q;
    q.x = pack2(lds[kvb + 0][cl], lds[kvb + 1][cl]);
    q.y = pack2(lds[kvb + 2][cl], lds[kvb + 3][cl]);
    q.z = pack2(lds[kvb + 4][cl], lds[kvb + 5][cl]);
    q.w = pack2(lds[kvb + 6][cl], lds[kvb + 7][cl]);
    Vf[(((size_t)nb * 128 + ktg * 4 + kt_loc) * 2 + ks) * 64 + lane] = q;
  }
}

// ------------- B-direct NT GEMM: A in LDS, B-frags direct from global ------
// BM x 256 tile, 512 thr (8 waves 2M x 4N). BK=64. ONE barrier per K-tile.
// KTSPAN: kt-dim extent of the B-frag layout (16 for Kfrag, 128 for Vfrag).
// DEC 0 = GEMM1 supertile decode; DEC 1 = GEMM2 bm-fastest decode.
// OUTMODE 0: C=bf16 exp(acc*scale) + per-wave row partials; 1: f32 acc*inv.
template <int BM, int KTSPAN, int OUTMODE, int DEC>
__global__ __launch_bounds__(512, 2) void gemm_bd(const u16* __restrict__ A,
                                                  const uint4* __restrict__ Bf,
                                                  void* __restrict__ Cv,
                                                  const float* __restrict__ inv,
                                                  float* __restrict__ partials,
                                                  int K, int ldc, float scale) {
  constexpr int MF = BM / 32;      // per-wave m-frags (8 or 4)
  constexpr int MH = MF / 2;
  constexpr int LA = BM / 128;     // A gloads/thread/tile... (BM*64*2/512/16)
  constexpr int LAJ = BM / 64;     // A j-batches of 64 rows (4 or 2)
  constexpr int ABUF = BM * 128;   // bytes per buffer
  __shared__ __align__(1024) char smem[2 * ABUF];

  const int tid = threadIdx.x;
  const int lane = tid & 63, wave = tid >> 6;
  const int wr = wave >> 2, wc = wave & 3;
  const int lan15 = lane & 15, g = lane >> 4, l7 = lane & 7;

  const int nwg = gridDim.x;
  const int wg = (blockIdx.x & 7) * (nwg >> 3) + (blockIdx.x >> 3);
  int bm0, bn0;
  if constexpr (DEC == 0) {
    const int r = wg & 255;
    bm0 = (r >> 3) * 256;
    bn0 = (((wg >> 8) << 3) | (r & 7)) * 256;
  } else {
    bm0 = (wg & 63) * BM;
    bn0 = (wg >> 6) * 256;
  }

  // A staging: thread -> row sr, swizzled col-block (both-sides XOR, verified)
  const int sr = tid >> 3;
  const int scb = ((tid & 7) ^ (sr & 7)) * 8;
  const u16* Ags = A + (size_t)(bm0 + sr) * K + scb;

  // A fragment-read offsets
  const int sa0 = ((0 + g) ^ l7) * 16;
  const int sa1 = ((4 + g) ^ l7) * 16;
  const int abase = (wr * (BM / 2) + lan15) * 128;

  // B frag base: n-block for this wave's n-frag n is nb0+n
  const int nb0 = (bn0 >> 4) + wc * 4;

  f32x4 acc[MF][4];
#pragma unroll
  for (int m = 0; m < MF; ++m)
#pragma unroll
    for (int n = 0; n < 4; ++n) acc[m][n] = f32x4{0.f, 0.f, 0.f, 0.f};

  const int nt = K >> 6;

  auto ISSUE_A = [&](int t) {
    char* bb = smem + (t & 1) * ABUF;
    const size_t ko = (size_t)t * 64;
#pragma unroll
    for (int j = 0; j < LAJ; ++j)
      __builtin_amdgcn_global_load_lds((as1p)(Ags + (size_t)j * 64 * K + ko),
                                       (as3p)(bb + j * 8192 + tid * 16), 16, 0, 0);
  };

  auto LOADB = [&](int t, bf16x8 (&bq)[4][2]) {
    const int tc = (t < nt) ? t : (nt - 1);
#pragma unroll
    for (int n = 0; n < 4; ++n)
#pragma unroll
      for (int ks = 0; ks < 2; ++ks) {
        const uint4 q = Bf[(((size_t)(nb0 + n) * KTSPAN + tc) * 2 + ks) * 64 + lane];
        bq[n][ks] = *(const bf16x8*)&q;
      }
  };

  bf16x8 bA[4][2], bB[4][2];

  // prologue: stage A(0), load B(0); force A(0) landed (B waits are compiler's)
  ISSUE_A(0);
  SCHED0();
  LOADB(0, bA);
  VM(8);
  BAR();

  auto TILE = [&](int t, bf16x8 (&bc)[4][2], bf16x8 (&bn_)[4][2]) {
    const char* bp = smem + (t & 1) * ABUF;
    // issue next A stage (other buffer), then next B frag loads
    if (t + 1 < nt) ISSUE_A(t + 1);
    SCHED0();
    LOADB(t + 1, bn_);
    // A frags mh0 + MFMA (free-run; compiler manages lgkm for own reads)
    bf16x8 a[MH][2];
#pragma unroll
    for (int m = 0; m < MH; ++m) {
      a[m][0] = *(const bf16x8*)(bp + abase + m * 2048 + sa0);
      a[m][1] = *(const bf16x8*)(bp + abase + m * 2048 + sa1);
    }
    __builtin_amdgcn_s_setprio(1);
#pragma unroll
    for (int m = 0; m < MH; ++m)
#pragma unroll
      for (int n = 0; n < 4; ++n)
#pragma unroll
        for (int ks = 0; ks < 2; ++ks)
          acc[m][n] = __builtin_amdgcn_mfma_f32_16x16x32_bf16(a[m][ks], bc[n][ks], acc[m][n], 0, 0, 0);
    __builtin_amdgcn_s_setprio(0);
    // A frags mh1 + MFMA
#pragma unroll
    for (int m = 0; m < MH; ++m) {
      a[m][0] = *(const bf16x8*)(bp + abase + (MH + m) * 2048 + sa0);
      a[m][1] = *(const bf16x8*)(bp + abase + (MH + m) * 2048 + sa1);
    }
    __builtin_amdgcn_s_setprio(1);
#pragma unroll
    for (int m = 0; m < MH; ++m)
#pragma unroll
      for (int n = 0; n < 4; ++n)
#pragma unroll
        for (int ks = 0; ks < 2; ++ks)
          acc[MH + m][n] = __builtin_amdgcn_mfma_f32_16x16x32_bf16(a[m][ks], bc[n][ks], acc[MH + m][n], 0, 0, 0);
    __builtin_amdgcn_s_setprio(0);
    // tile boundary: own ds_reads drained; A(t+1) landed (B(t+1) in flight)
    LGKM0();
    if (t + 1 < nt) { VM(8); } else { VM(0); }
    BAR();
  };

  for (int t = 0; t < nt; t += 2) {
    TILE(t, bA, bB);
    TILE(t + 1, bB, bA);
  }

  // ---- epilogue. C/D map: col = lane&15, row = (lane>>4)*4 + reg
  const int c0 = bn0 + wc * 64 + lan15;
  if constexpr (OUTMODE == 0) {
    u16* C = (u16*)Cv;
    const int cb4 = (bn0 >> 8) * 4 + wc;
#pragma unroll
    for (int m = 0; m < MF; ++m)
#pragma unroll
      for (int r = 0; r < 4; ++r) {
        const int row = bm0 + wr * (BM / 2) + m * 16 + g * 4 + r;
        float part = 0.f;
#pragma unroll
        for (int n = 0; n < 4; ++n) {
          float v = __expf(acc[m][n][r] * scale);
          C[(size_t)row * ldc + c0 + n * 16] = f2bf(v);
          part += v;
        }
        part += __shfl_xor(part, 1, 64);
        part += __shfl_xor(part, 2, 64);
        part += __shfl_xor(part, 4, 64);
        part += __shfl_xor(part, 8, 64);
        if (lan15 == 0) partials[(size_t)row * 128 + cb4] = part;
      }
  } else {
    float* C = (float*)Cv;
#pragma unroll
    for (int m = 0; m < MF; ++m)
#pragma unroll
      for (int r = 0; r < 4; ++r) {
        const int row = bm0 + wr * (BM / 2) + m * 16 + g * 4 + r;
        const float iv = inv ? inv[row] : 1.0f;
#pragma unroll
        for (int n = 0; n < 4; ++n)
          C[(size_t)row * ldc + c0 + n * 16] = acc[m][n][r] * iv;
      }
  }
}

// ---------------- inv[row] = 1 / sum_j partials[row][j] --------------------
__global__ __launch_bounds__(256) void rowinv(const float* __restrict__ partials,
                                              float* __restrict__ inv) {
  const int row = blockIdx.x * 256 + threadIdx.x;
  const float4* p = (const float4*)(partials + (size_t)row * 128);
  float s = 0.f;
#pragma unroll
  for (int j = 0; j < 32; ++j) {
    float4 v = p[j];
    s += (v.x + v.y) + (v.z + v.w);
  }
  inv[row] = 1.0f / s;
}

// --------------- fallback: normalize E rows in place (bf16) ----------------
__global__ __launch_bounds__(256) void normalize_inplace(u16* __restrict__ E) {
  __shared__ float red[4];
  u16* row = E + (size_t)blockIdx.x * 8192;
  const int tid = threadIdx.x;
  float f[32];
  float s = 0.f;
#pragma unroll
  for (int c = 0; c < 4; ++c) {
    uint4 v = *((const uint4*)row + c * 256 + tid);
    unsigned u[4] = {v.x, v.y, v.z, v.w};
#pragma unroll
    for (int q = 0; q < 4; ++q) {
      f[c * 8 + q * 2] = bf2f((u16)(u[q] & 0xffffu));
      f[c * 8 + q * 2 + 1] = bf2f((u16)(u[q] >> 16));
      s += f[c * 8 + q * 2] + f[c * 8 + q * 2 + 1];
    }
  }
#pragma unroll
  for (int off = 32; off; off >>= 1) s += __shfl_xor(s, off, 64);
  if ((tid & 63) == 0) red[tid >> 6] = s;
  __syncthreads();
  const float iv = 1.0f / ((red[0] + red[1]) + (red[2] + red[3]));
#pragma unroll
  for (int c = 0; c < 4; ++c) {
    uint4 o;
    o.x = pack2(f[c * 8 + 0] * iv, f[c * 8 + 1] * iv);
    o.y = pack2(f[c * 8 + 2] * iv, f[c * 8 + 3] * iv);
    o.z = pack2(f[c * 8 + 4] * iv, f[c * 8 + 5] * iv);
    o.w = pack2(f[c * 8 + 6] * iv, f[c * 8 + 7] * iv);
    *((uint4*)row + c * 256 + tid) = o;
  }
}

// ---------------------------------------------------------------------------
extern "C" void kernel_launch(void* const* d_in, const int* in_sizes, int n_in,
                              void* d_out, int out_size, void* d_ws, size_t ws_size,
                              hipStream_t stream) {
  const float* Q = (const float*)d_in[0];
  const float* K = (const float*)d_in[1];
  const float* V = (const float*)d_in[2];

  char* ws = (char*)d_ws;
  u16* S = (u16*)ws;                                              // 128 MB
  uint4* Vf = (uint4*)(ws + (size_t)134217728);                   // 16 MB frag-V
  float* partials = (float*)(ws + (size_t)134217728 + 16777216);  // 4 MB
  float* inv = (float*)(ws + (size_t)134217728 + 16777216 + 4194304);
  const bool haveInv =
      ws_size >= (size_t)134217728 + 16777216 + 4194304 + 32768;

  u16* Qb = (u16*)d_out;                  // bf16 Q row-major (16 MB)
  uint4* Kf = (uint4*)((char*)d_out + 16777216);  // frag-K (16 MB)

  cvt_bf16<<<4096, 256, 0, stream>>>(Q, Qb);
  kfrag_write<<<dim3(512, 4), 256, 0, stream>>>(K, Kf);
  vfrag_write<<<dim3(64, 32), 256, 0, stream>>>(V, Vf);

  // E = exp(Q K^T / 32)  [8192 x 8192] bf16 ; grid 1024 (supertile decode)
  gemm_bd<256, 16, 0, 0><<<1024, 512, 0, stream>>>(
      Qb, Kf, S, nullptr, haveInv ? partials : (float*)(ws + 134217728 + 16777216),
      1024, 8192, 1.0f / 32.0f);

  if (haveInv) {
    rowinv<<<32, 256, 0, stream>>>(partials, inv);
    // O = diag(inv) E V  [8192 x 1024] f32 ; grid 256 (bm-fastest decode)
    gemm_bd<128, 128, 1, 1><<<256, 512, 0, stream>>>(
        S, Vf, d_out, inv, nullptr, 8192, 1024, 1.0f);
  } else {
    normalize_inplace<<<8192, 256, 0, stream>>>(S);
    gemm_bd<128, 128, 1, 1><<<256, 512, 0, stream>>>(
        S, Vf, d_out, nullptr, nullptr, 8192, 1024, 1.0f);
  }
}

// Round 11
// 309.222 us; speedup vs baseline: 1.0854x; 1.0830x over previous
//
#include <hip/hip_runtime.h>
#include <hip/hip_bf16.h>

// ---------------------------------------------------------------------------
// attention via: E = exp(QK^T/32) (bf16), inv[r] = 1/sum_k E[r,k] (per-wave
// partials), O = diag(inv)*E*V.
// r11: software-pipelined quadrant GEMM. Insight (r10 arithmetic): MFMA and
// LDS pipe demands are ~equal (~2.5k cyc/CU/K-tile each); all prior variants
// serialized them (5.6k cyc/tile observed). Fix: issue every ds_read batch
// one MFMA-quadrant BEFORE its use; the compiler's automatic counted
// lgkmcnt(N) then overlaps LDS service with the previous quadrant's MFMAs.
//   per tile: BAR; ISSUE DMA(t+D-1); rd B1; Q0(A0,B0); rd A1; Q1(A0,B1);
//             VM-certify buf(t+1) (counted, 2-tile cover at DEPTH=3);
//             Q2(A1,B0); rd A0,B0(t+1) [buf t+1 certified]; Q3(A1,B1)
// GEMM1: BM=BN=256, DEPTH=2 (128KB LDS), K=1024, supertile decode (96MB).
// GEMM2: BM=128,BN=256, DEPTH=3 (144KB), K=8192, bm-fastest decode.
// T2 both-sides XOR swizzle (0 conflicts verified), T5 setprio kept.
// ws: [0,128MB)=E ; [128MB,144MB)=V^T ; [144MB,148MB)=partials ; then inv.
// d_out holds bf16 Q|K scratch until GEMM2 overwrites it.
// ---------------------------------------------------------------------------

typedef __bf16 bf16x8 __attribute__((ext_vector_type(8)));
typedef float f32x4 __attribute__((ext_vector_type(4)));
typedef const __attribute__((address_space(1))) unsigned int* as1p;
typedef __attribute__((address_space(3))) unsigned int* as3p;
typedef unsigned short u16;

__device__ __forceinline__ u16 f2bf(float x) {
  unsigned u = __float_as_uint(x);
  u += 0x7fffu + ((u >> 16) & 1u);
  return (u16)(u >> 16);
}
__device__ __forceinline__ float bf2f(u16 b) { return __uint_as_float(((unsigned)b) << 16); }
__device__ __forceinline__ unsigned pack2(float lo, float hi) {
  return (unsigned)f2bf(lo) | ((unsigned)f2bf(hi) << 16);
}

#define BAR()   do { __builtin_amdgcn_s_barrier(); asm volatile("" ::: "memory"); } while (0)
#define VM(n)   do { asm volatile("s_waitcnt vmcnt(" #n ")" ::: "memory"); __builtin_amdgcn_sched_barrier(0); } while (0)

// --------------------------- f32 -> bf16 convert ---------------------------
__global__ __launch_bounds__(256) void cvt_bf16(const float* __restrict__ in,
                                                unsigned short* __restrict__ out) {
  const size_t i = (size_t)blockIdx.x * 256 + threadIdx.x;
  const float4* p = (const float4*)in + i * 2;
  float4 a = p[0], b = p[1];
  uint4 o;
  o.x = pack2(a.x, a.y);
  o.y = pack2(a.z, a.w);
  o.z = pack2(b.x, b.y);
  o.w = pack2(b.z, b.w);
  ((uint4*)out)[i] = o;
}

// ------------- V [8192,1024] f32 -> V^T [1024,8192] bf16 -------------------
__global__ __launch_bounds__(256) void transpose_bf16(const float* __restrict__ V,
                                                      unsigned short* __restrict__ VT) {
  __shared__ float t[64][65];
  const int rb = blockIdx.x * 64;
  const int cb = blockIdx.y * 64;
  const int tid = threadIdx.x;
#pragma unroll
  for (int it = 0; it < 4; ++it) {
    int r = it * 16 + (tid >> 4);
    int c = (tid & 15) * 4;
    float4 x = *(const float4*)(V + (size_t)(rb + r) * 1024 + cb + c);
    t[r][c] = x.x; t[r][c + 1] = x.y; t[r][c + 2] = x.z; t[r][c + 3] = x.w;
  }
  __syncthreads();
  const int j = tid & 63;
  const int c0 = (tid >> 6) * 16;
#pragma unroll
  for (int i = 0; i < 16; ++i) {
    int c = c0 + i;
    VT[(size_t)(cb + c) * 8192 + rb + j] = f2bf(t[j][c]);
  }
}

// ---------------- pipelined quadrant NT GEMM (1 barrier/tile) --------------
// C[M,N](ldc) = A[M,K]*B[N,K]^T, BN=256. 512 threads, 8 waves (2M x 4N).
// DEC 0: grid 1024 = supertile 16bm x 8bn per XCD chunk   [GEMM1]
// DEC 1: grid 256  = bm-fastest, VT quadrant L2-resident  [GEMM2]
// OUTMODE 0: C=bf16 exp(acc*scale) + per-wave row partials.
// OUTMODE 1: C=f32 acc*inv[row].
template <int BM, int DEPTH, int OUTMODE, int DEC>
__global__ __launch_bounds__(512, 2) void gemm_pl(const u16* __restrict__ A,
                                                  const u16* __restrict__ B,
                                                  void* __restrict__ Cv,
                                                  const float* __restrict__ inv,
                                                  float* __restrict__ partials,
                                                  int K, int ldc, float scale) {
  constexpr int MF = BM / 32;       // per-wave m-frags (8 or 4)
  constexpr int MH = MF / 2;        // m-frags per half (4 or 2)
  constexpr int LAJ = BM / 64;      // A stage batches (4 or 2)
  constexpr int LPT = LAJ + 4;      // DMA loads/thread/tile (8 or 6)
  constexpr int ABUF = BM * 128;
  constexpr int BBUF = 32768;
  constexpr int BUFSZ = ABUF + BBUF;
  __shared__ __align__(1024) char smem[DEPTH * BUFSZ];

  const int tid = threadIdx.x;
  const int lane = tid & 63, wave = tid >> 6;
  const int wr = wave >> 2, wc = wave & 3;
  const int lan15 = lane & 15, g = lane >> 4, l7 = lane & 7;

  // T1: bijective XCD swizzle (nwg % 8 == 0 at both call sites)
  const int nwg = gridDim.x;
  const int wg = (blockIdx.x & 7) * (nwg >> 3) + (blockIdx.x >> 3);
  int bm0, bn0;
  if constexpr (DEC == 0) {
    const int r = wg & 255;
    bm0 = (r >> 3) * 256;
    bn0 = (((wg >> 8) << 3) | (r & 7)) * 256;
  } else {
    bm0 = (wg & 63) * BM;
    bn0 = (wg >> 6) * 256;
  }

  // staging: thread -> row (tid>>3), swizzled src col-block (tid&7)^(row&7)
  const int sr = tid >> 3;
  const int scb = ((tid & 7) ^ (sr & 7)) * 8;
  const u16* Ags = A + (size_t)(bm0 + sr) * K + scb;
  const u16* Bgs = B + (size_t)(bn0 + sr) * K + scb;

  // fragment-read swizzled 16B-slot offsets
  const int sa0 = ((0 + g) ^ l7) * 16;
  const int sa1 = ((4 + g) ^ l7) * 16;
  const int abase = (wr * (BM / 2) + lan15) * 128;
  const int bbase = ABUF + (wc * 64 + lan15) * 128;

  f32x4 acc[MF][4];
#pragma unroll
  for (int m = 0; m < MF; ++m)
#pragma unroll
    for (int n = 0; n < 4; ++n) acc[m][n] = f32x4{0.f, 0.f, 0.f, 0.f};

  const int nt = K >> 6;

  auto ISSUE = [&](int t) {
    char* bb = smem + (t % DEPTH) * BUFSZ;
    const size_t ko = (size_t)t * 64;
#pragma unroll
    for (int j = 0; j < LAJ; ++j)
      __builtin_amdgcn_global_load_lds((as1p)(Ags + (size_t)j * 64 * K + ko),
                                       (as3p)(bb + j * 8192 + tid * 16), 16, 0, 0);
#pragma unroll
    for (int j = 0; j < 4; ++j)
      __builtin_amdgcn_global_load_lds((as1p)(Bgs + (size_t)j * 64 * K + ko),
                                       (as3p)(bb + ABUF + j * 8192 + tid * 16), 16, 0, 0);
  };

  // fragment register sets (all live: ~(2*MH+4) b128 + acc)
  bf16x8 A0[MH][2], A1[MH][2], B0[2][2], B1[2][2];

  auto RD_A0 = [&](int t) {
    const char* bp = smem + (t % DEPTH) * BUFSZ;
#pragma unroll
    for (int m = 0; m < MH; ++m) {
      A0[m][0] = *(const bf16x8*)(bp + abase + m * 2048 + sa0);
      A0[m][1] = *(const bf16x8*)(bp + abase + m * 2048 + sa1);
    }
  };
  auto RD_A1 = [&](int t) {
    const char* bp = smem + (t % DEPTH) * BUFSZ;
#pragma unroll
    for (int m = 0; m < MH; ++m) {
      A1[m][0] = *(const bf16x8*)(bp + abase + (MH + m) * 2048 + sa0);
      A1[m][1] = *(const bf16x8*)(bp + abase + (MH + m) * 2048 + sa1);
    }
  };
  auto RD_B0 = [&](int t) {
    const char* bp = smem + (t % DEPTH) * BUFSZ;
#pragma unroll
    for (int n = 0; n < 2; ++n) {
      B0[n][0] = *(const bf16x8*)(bp + bbase + n * 2048 + sa0);
      B0[n][1] = *(const bf16x8*)(bp + bbase + n * 2048 + sa1);
    }
  };
  auto RD_B1 = [&](int t) {
    const char* bp = smem + (t % DEPTH) * BUFSZ;
#pragma unroll
    for (int n = 0; n < 2; ++n) {
      B1[n][0] = *(const bf16x8*)(bp + bbase + (2 + n) * 2048 + sa0);
      B1[n][1] = *(const bf16x8*)(bp + bbase + (2 + n) * 2048 + sa1);
    }
  };

  auto Q = [&](bf16x8 (&a)[MH][2], bf16x8 (&b)[2][2], int mo, int no) {
    __builtin_amdgcn_s_setprio(1);
#pragma unroll
    for (int m = 0; m < MH; ++m)
#pragma unroll
      for (int n = 0; n < 2; ++n)
#pragma unroll
        for (int ks = 0; ks < 2; ++ks)
          acc[mo + m][no + n] = __builtin_amdgcn_mfma_f32_16x16x32_bf16(
              a[m][ks], b[n][ks], acc[mo + m][no + n], 0, 0, 0);
    __builtin_amdgcn_s_setprio(0);
  };

  // ---- prologue: stage buf0 (+buf1 at DEPTH=3); certify buf0; read Q0 set
  ISSUE(0);
  if constexpr (DEPTH == 3) {
    ISSUE(1);
    if constexpr (LPT == 8) { VM(8); } else { VM(6); }
  } else {
    VM(0);
  }
  BAR();
  RD_A0(0); RD_B0(0);

  for (int t = 0; t < nt; ++t) {
    BAR();  // all waves done reading buf((t-1)%D) -> safe to overwrite
    if constexpr (DEPTH == 2) {
      if (t + 1 < nt) ISSUE(t + 1);
    } else {
      if (t + 2 < nt) ISSUE(t + 2);
    }
    RD_B1(t);
    Q(A0, B0, 0, 0);   // compiler waits A0,B0 (issued prev Q3), B1 in flight
    RD_A1(t);
    Q(A0, B1, 0, 2);
    // certify buf(t+1) DMA landed (counted at DEPTH=3: t+2 stays in flight)
    if constexpr (DEPTH == 2) {
      if (t + 1 < nt) { VM(0); }
    } else {
      if (t + 2 < nt) {
        if constexpr (LPT == 8) { VM(8); } else { VM(6); }
      } else if (t + 1 < nt) {
        VM(0);
      }
    }
    Q(A1, B0, MH, 0);
    if (t + 1 < nt) { RD_A0(t + 1); RD_B0(t + 1); }  // buf(t+1) certified
    Q(A1, B1, MH, 2);
  }

  // ---- epilogue. C/D map: col = lane&15, row = (lane>>4)*4 + reg
  const int c0 = bn0 + wc * 64 + lan15;
  if constexpr (OUTMODE == 0) {
    u16* C = (u16*)Cv;
    const int cb4 = (bn0 >> 8) * 4 + wc;  // partial-column index (0..127)
#pragma unroll
    for (int m = 0; m < MF; ++m)
#pragma unroll
      for (int r = 0; r < 4; ++r) {
        const int row = bm0 + wr * (BM / 2) + m * 16 + g * 4 + r;
        float part = 0.f;
#pragma unroll
        for (int n = 0; n < 4; ++n) {
          float v = __expf(acc[m][n][r] * scale);
          C[(size_t)row * ldc + c0 + n * 16] = f2bf(v);
          part += v;
        }
        part += __shfl_xor(part, 1, 64);
        part += __shfl_xor(part, 2, 64);
        part += __shfl_xor(part, 4, 64);
        part += __shfl_xor(part, 8, 64);
        if (lan15 == 0) partials[(size_t)row * 128 + cb4] = part;
      }
  } else {
    float* C = (float*)Cv;
#pragma unroll
    for (int m = 0; m < MF; ++m)
#pragma unroll
      for (int r = 0; r < 4; ++r) {
        const int row = bm0 + wr * (BM / 2) + m * 16 + g * 4 + r;
        const float iv = inv ? inv[row] : 1.0f;
#pragma unroll
        for (int n = 0; n < 4; ++n)
          C[(size_t)row * ldc + c0 + n * 16] = acc[m][n][r] * iv;
      }
  }
}

// ---------------- inv[row] = 1 / sum_j partials[row][j] --------------------
__global__ __launch_bounds__(256) void rowinv(const float* __restrict__ partials,
                                              float* __restrict__ inv) {
  const int row = blockIdx.x * 256 + threadIdx.x;
  const float4* p = (const float4*)(partials + (size_t)row * 128);
  float s = 0.f;
#pragma unroll
  for (int j = 0; j < 32; ++j) {
    float4 v = p[j];
    s += (v.x + v.y) + (v.z + v.w);
  }
  inv[row] = 1.0f / s;
}

// --------------- fallback: normalize E rows in place (bf16) ----------------
__global__ __launch_bounds__(256) void normalize_inplace(u16* __restrict__ E) {
  __shared__ float red[4];
  u16* row = E + (size_t)blockIdx.x * 8192;
  const int tid = threadIdx.x;
  float f[32];
  float s = 0.f;
#pragma unroll
  for (int c = 0; c < 4; ++c) {
    uint4 v = *((const uint4*)row + c * 256 + tid);
    unsigned u[4] = {v.x, v.y, v.z, v.w};
#pragma unroll
    for (int q = 0; q < 4; ++q) {
      f[c * 8 + q * 2] = bf2f((u16)(u[q] & 0xffffu));
      f[c * 8 + q * 2 + 1] = bf2f((u16)(u[q] >> 16));
      s += f[c * 8 + q * 2] + f[c * 8 + q * 2 + 1];
    }
  }
#pragma unroll
  for (int off = 32; off; off >>= 1) s += __shfl_xor(s, off, 64);
  if ((tid & 63) == 0) red[tid >> 6] = s;
  __syncthreads();
  const float iv = 1.0f / ((red[0] + red[1]) + (red[2] + red[3]));
#pragma unroll
  for (int c = 0; c < 4; ++c) {
    uint4 o;
    o.x = pack2(f[c * 8 + 0] * iv, f[c * 8 + 1] * iv);
    o.y = pack2(f[c * 8 + 2] * iv, f[c * 8 + 3] * iv);
    o.z = pack2(f[c * 8 + 4] * iv, f[c * 8 + 5] * iv);
    o.w = pack2(f[c * 8 + 6] * iv, f[c * 8 + 7] * iv);
    *((uint4*)row + c * 256 + tid) = o;
  }
}

// ---------------------------------------------------------------------------
extern "C" void kernel_launch(void* const* d_in, const int* in_sizes, int n_in,
                              void* d_out, int out_size, void* d_ws, size_t ws_size,
                              hipStream_t stream) {
  const float* Q = (const float*)d_in[0];
  const float* K = (const float*)d_in[1];
  const float* V = (const float*)d_in[2];

  char* ws = (char*)d_ws;
  u16* S = (u16*)ws;                                              // 128 MB
  u16* VT = (u16*)(ws + (size_t)134217728);                       // 16 MB
  float* partials = (float*)(ws + (size_t)134217728 + 16777216);  // 4 MB
  float* inv = (float*)(ws + (size_t)134217728 + 16777216 + 4194304);
  const bool haveInv =
      ws_size >= (size_t)134217728 + 16777216 + 4194304 + 32768;

  u16* Qb = (u16*)d_out;   // bf16 Q scratch (16 MB)
  u16* Kb = Qb + 8388608;  // bf16 K scratch (16 MB)

  cvt_bf16<<<4096, 256, 0, stream>>>(Q, Qb);
  cvt_bf16<<<4096, 256, 0, stream>>>(K, Kb);
  transpose_bf16<<<dim3(128, 16), 256, 0, stream>>>(V, VT);

  // E = exp(Q K^T / 32)  [8192 x 8192] bf16 ; grid 1024 (supertile decode)
  gemm_pl<256, 2, 0, 0><<<1024, 512, 0, stream>>>(
      Qb, Kb, S, nullptr, haveInv ? partials : (float*)(ws + 134217728 + 16777216),
      1024, 8192, 1.0f / 32.0f);

  if (haveInv) {
    rowinv<<<32, 256, 0, stream>>>(partials, inv);
    // O = diag(inv) E V  [8192 x 1024] f32 ; grid 256 (bm-fastest decode)
    gemm_pl<128, 3, 1, 1><<<256, 512, 0, stream>>>(
        S, VT, d_out, inv, nullptr, 8192, 1024, 1.0f);
  } else {
    normalize_inplace<<<8192, 256, 0, stream>>>(S);
    gemm_pl<128, 3, 1, 1><<<256, 512, 0, stream>>>(
        S, VT, d_out, nullptr, nullptr, 8192, 1024, 1.0f);
  }
}

// Round 12
// 304.331 us; speedup vs baseline: 1.1028x; 1.0161x over previous
//
#include <hip/hip_runtime.h>
#include <hip/hip_bf16.h>

// ---------------------------------------------------------------------------
// attention via: E = exp(QK^T/32) (bf16), inv[r] = 1/sum_k E[r,k] (per-wave
// partials), O = diag(inv)*E*V.
// r12: m201 8-phase schedule with CORRECT pipeline depth. Iteration = 2
// K-tiles (buf0: ph0-3, buf1: ph4-7). Staging runs TWO K-tiles ahead into
// just-freed regions of the same double buffer (one unit per phase):
//   ph0: A-mh1(t0+1)  ph1: A-mh0(t0+2)  ph2: B-lo(t0+2)  ph3: B-hi(t0+2)
//   ph4: A-mh1(t0+2)  ph5: A-mh0(t0+3)  ph6: B-lo(t0+3)  ph7: B-hi(t0+3)
// (region death: A-mh0{j0,j2}@ph0, B@ph1, A-mh1{j1,j3}@ph2; +4 for buf1)
// Counted waits ONLY at ph3/ph7: VM(6) [BM=256] / VM(4) [BM=128] — forces
// exactly the next tile's units, leads 3.5-6.5 phases (~2200+ cyc >> HBM).
// Phase body: {ds_reads; stage; BAR; lgkm0; setprio 16/8xMFMA; BAR}.
// T2 both-sides XOR swizzle (0 conflicts), T5 setprio.
// Decodes: GEMM1 supertile 16x8/XCD (FETCH 96MB verified); GEMM2 NEW
// 8bm x 4bn per XCD chunk (S-stripe sharing within one L2).
// ws: [0,128MB)=E ; [128MB,144MB)=V^T ; [144MB,148MB)=partials ; then inv.
// d_out holds bf16 Q|K scratch until GEMM2 overwrites it.
// ---------------------------------------------------------------------------

typedef __bf16 bf16x8 __attribute__((ext_vector_type(8)));
typedef float f32x4 __attribute__((ext_vector_type(4)));
typedef const __attribute__((address_space(1))) unsigned int* as1p;
typedef __attribute__((address_space(3))) unsigned int* as3p;
typedef unsigned short u16;

__device__ __forceinline__ u16 f2bf(float x) {
  unsigned u = __float_as_uint(x);
  u += 0x7fffu + ((u >> 16) & 1u);
  return (u16)(u >> 16);
}
__device__ __forceinline__ float bf2f(u16 b) { return __uint_as_float(((unsigned)b) << 16); }
__device__ __forceinline__ unsigned pack2(float lo, float hi) {
  return (unsigned)f2bf(lo) | ((unsigned)f2bf(hi) << 16);
}

#define BAR()   do { __builtin_amdgcn_s_barrier(); asm volatile("" ::: "memory"); } while (0)
#define LGKM0() do { asm volatile("s_waitcnt lgkmcnt(0)" ::: "memory"); __builtin_amdgcn_sched_barrier(0); } while (0)
#define VM(n)   do { asm volatile("s_waitcnt vmcnt(" #n ")" ::: "memory"); __builtin_amdgcn_sched_barrier(0); } while (0)

// --------------------------- f32 -> bf16 convert ---------------------------
__global__ __launch_bounds__(256) void cvt_bf16(const float* __restrict__ in,
                                                unsigned short* __restrict__ out) {
  const size_t i = (size_t)blockIdx.x * 256 + threadIdx.x;
  const float4* p = (const float4*)in + i * 2;
  float4 a = p[0], b = p[1];
  uint4 o;
  o.x = pack2(a.x, a.y);
  o.y = pack2(a.z, a.w);
  o.z = pack2(b.x, b.y);
  o.w = pack2(b.z, b.w);
  ((uint4*)out)[i] = o;
}

// ------------- V [8192,1024] f32 -> V^T [1024,8192] bf16 -------------------
__global__ __launch_bounds__(256) void transpose_bf16(const float* __restrict__ V,
                                                      unsigned short* __restrict__ VT) {
  __shared__ float t[64][65];
  const int rb = blockIdx.x * 64;
  const int cb = blockIdx.y * 64;
  const int tid = threadIdx.x;
#pragma unroll
  for (int it = 0; it < 4; ++it) {
    int r = it * 16 + (tid >> 4);
    int c = (tid & 15) * 4;
    float4 x = *(const float4*)(V + (size_t)(rb + r) * 1024 + cb + c);
    t[r][c] = x.x; t[r][c + 1] = x.y; t[r][c + 2] = x.z; t[r][c + 3] = x.w;
  }
  __syncthreads();
  const int j = tid & 63;
  const int c0 = (tid >> 6) * 16;
#pragma unroll
  for (int i = 0; i < 16; ++i) {
    int c = c0 + i;
    VT[(size_t)(cb + c) * 8192 + rb + j] = f2bf(t[j][c]);
  }
}

// -------------- 8-phase NT GEMM, 2-tile-ahead staging (m201-depth) ---------
// C[M,N](ldc) = A[M,K]*B[N,K]^T, BN=256. 512 threads, 8 waves (2M x 4N).
// DEC 0: grid 1024 = supertile 16bm x 8bn per XCD chunk   [GEMM1]
// DEC 1: grid 256  = 8bm x 4bn per XCD chunk (bn fastest) [GEMM2]
// OUTMODE 0: C=bf16 exp(acc*scale) + per-wave row partials.
// OUTMODE 1: C=f32 acc*inv[row].
template <int BM, int OUTMODE, int DEC>
__global__ __launch_bounds__(512, 2) void gemm8d(const u16* __restrict__ A,
                                                 const u16* __restrict__ B,
                                                 void* __restrict__ Cv,
                                                 const float* __restrict__ inv,
                                                 float* __restrict__ partials,
                                                 int K, int ldc, float scale) {
  constexpr int MF = BM / 32;       // per-wave m-frags (8 or 4)
  constexpr int MH = MF / 2;        // m-frags per half
  constexpr int ABUF = BM * 128;
  constexpr int BBUF = 32768;
  constexpr int BUFSZ = ABUF + BBUF;
  __shared__ __align__(1024) char smem[2 * BUFSZ];

  const int tid = threadIdx.x;
  const int lane = tid & 63, wave = tid >> 6;
  const int wr = wave >> 2, wc = wave & 3;
  const int lan15 = lane & 15, g = lane >> 4, l7 = lane & 7;

  // T1: bijective XCD swizzle (nwg % 8 == 0 at both call sites)
  const int nwg = gridDim.x;
  const int wg = (blockIdx.x & 7) * (nwg >> 3) + (blockIdx.x >> 3);
  int bm0, bn0;
  if constexpr (DEC == 0) {
    const int r = wg & 255;
    bm0 = (r >> 3) * 256;
    bn0 = (((wg >> 8) << 3) | (r & 7)) * 256;
  } else {
    // 256 wgs: XCD chunk of 32 = 8 bm x 4 bn, bn fastest -> the 4 blocks
    // sharing an S-row-stripe sit on ONE XCD (L2 serves 3 of 4 reads).
    const int chunk = wg >> 5;       // == source XCD
    const int within = wg & 31;
    bm0 = (chunk * 8 + (within >> 2)) * BM;
    bn0 = (within & 3) * 256;
  }

  // staging: thread -> row (tid>>3), swizzled src col-block (tid&7)^(row&7)
  const int sr = tid >> 3;
  const int scb = ((tid & 7) ^ (sr & 7)) * 8;
  const u16* Ags = A + (size_t)(bm0 + sr) * K + scb;
  const u16* Bgs = B + (size_t)(bn0 + sr) * K + scb;

  // fragment-read swizzled 16B-slot offsets
  const int sa0 = ((0 + g) ^ l7) * 16;
  const int sa1 = ((4 + g) ^ l7) * 16;
  const int abase = (wr * (BM / 2) + lan15) * 128;
  const int bbase = ABUF + (wc * 64 + lan15) * 128;

  f32x4 acc[MF][4];
#pragma unroll
  for (int m = 0; m < MF; ++m)
#pragma unroll
    for (int n = 0; n < 4; ++n) acc[m][n] = f32x4{0.f, 0.f, 0.f, 0.f};

  const int nt = K >> 6;
  const int niter = nt >> 1;

  // stage units: 2 x global_load_lds each, explicit j-batches (64 rows each)
  auto IA = [&](int t, int ja, int jb) {
    char* bb = smem + (t & 1) * BUFSZ;
    const size_t ko = (size_t)t * 64;
    __builtin_amdgcn_global_load_lds((as1p)(Ags + (size_t)ja * 64 * K + ko),
                                     (as3p)(bb + ja * 8192 + tid * 16), 16, 0, 0);
    __builtin_amdgcn_global_load_lds((as1p)(Ags + (size_t)jb * 64 * K + ko),
                                     (as3p)(bb + jb * 8192 + tid * 16), 16, 0, 0);
  };
  auto IB = [&](int t, int j0) {  // batches j0, j0+1
    char* bb = smem + (t & 1) * BUFSZ + ABUF;
    const size_t ko = (size_t)t * 64;
    __builtin_amdgcn_global_load_lds((as1p)(Bgs + (size_t)j0 * 64 * K + ko),
                                     (as3p)(bb + j0 * 8192 + tid * 16), 16, 0, 0);
    __builtin_amdgcn_global_load_lds((as1p)(Bgs + (size_t)(j0 + 1) * 64 * K + ko),
                                     (as3p)(bb + (j0 + 1) * 8192 + tid * 16), 16, 0, 0);
  };
  // A-mh0 region = j{0,2} (BM=256) / whole A after mh1-read (BM=128)
  auto IA_mh0 = [&](int t) { if constexpr (BM == 256) IA(t, 0, 2); };
  auto IA_mh1 = [&](int t) { if constexpr (BM == 256) IA(t, 1, 3); else IA(t, 0, 1); };

  bf16x8 a[MH][2], b[4][2];
  auto DS_A = [&](int bb, int mh) {
#pragma unroll
    for (int m = 0; m < MH; ++m) {
      a[m][0] = *(const bf16x8*)(smem + bb + abase + (mh * MH + m) * 2048 + sa0);
      a[m][1] = *(const bf16x8*)(smem + bb + abase + (mh * MH + m) * 2048 + sa1);
    }
  };
  auto DS_B = [&](int bb, int nh) {
#pragma unroll
    for (int n = 0; n < 2; ++n) {
      b[nh * 2 + n][0] = *(const bf16x8*)(smem + bb + bbase + (nh * 2 + n) * 2048 + sa0);
      b[nh * 2 + n][1] = *(const bf16x8*)(smem + bb + bbase + (nh * 2 + n) * 2048 + sa1);
    }
  };
  auto MMA = [&](int mh, int nh) {
    __builtin_amdgcn_s_setprio(1);
#pragma unroll
    for (int m = 0; m < MH; ++m)
#pragma unroll
      for (int n = 0; n < 2; ++n)
#pragma unroll
        for (int ks = 0; ks < 2; ++ks)
          acc[mh * MH + m][nh * 2 + n] = __builtin_amdgcn_mfma_f32_16x16x32_bf16(
              a[m][ks], b[nh * 2 + n][ks], acc[mh * MH + m][nh * 2 + n], 0, 0, 0);
    __builtin_amdgcn_s_setprio(0);
  };

  // ---- prologue: tile0 fully + tile1 {A-mh0, B}; force tile0 landed.
  // in-flight after VM: tile1's units (6 loads BM=256 / 4 loads BM=128).
  if constexpr (BM == 256) {
    IA(0, 0, 2); IB(0, 0); IB(0, 2); IA(0, 1, 3);
    IA(1, 0, 2); IB(1, 0); IB(1, 2);
    VM(6);
  } else {
    IB(0, 0); IB(0, 2); IA(0, 0, 1);
    IB(1, 0); IB(1, 2);
    VM(4);
  }
  BAR();

  for (int i = 0; i < niter; ++i) {
    const int t0 = 2 * i;
    const bool more = (i + 1 < niter);

    // ---- ph0: buf0 (mh0,nh0); stage A-mh1(t0+1) [buf1 mh1 died prev ph6]
    DS_A(0, 0); DS_B(0, 0);
    IA_mh1(t0 + 1);
    BAR(); LGKM0(); MMA(0, 0); BAR();

    // ---- ph1: buf0 (mh0,nh1); stage A-mh0(t0+2) [buf0 mh0 died ph0]
    DS_B(0, 1);
    if (more) IA_mh0(t0 + 2);
    BAR(); LGKM0(); MMA(0, 1); BAR();

    // ---- ph2: buf0 (mh1,nh0); stage B-lo(t0+2) [buf0 B died ph1]
    DS_A(0, 1);
    if (more) IB(t0 + 2, 0);
    BAR(); LGKM0(); MMA(1, 0); BAR();

    // ---- ph3: buf0 (mh1,nh1); stage B-hi(t0+2); certify tile t0+1
    if (more) IB(t0 + 2, 2);
    BAR(); MMA(1, 1);
    if (more) { if constexpr (BM == 256) VM(6); else VM(4); } else { VM(0); }
    BAR();

    // ---- ph4: buf1 (mh0,nh0); stage A-mh1(t0+2) [buf0 mh1 died ph2]
    DS_A(BUFSZ, 0); DS_B(BUFSZ, 0);
    if (more) IA_mh1(t0 + 2);
    BAR(); LGKM0(); MMA(0, 0); BAR();

    // ---- ph5: buf1 (mh0,nh1); stage A-mh0(t0+3) [buf1 mh0 died ph4]
    DS_B(BUFSZ, 1);
    if (more) IA_mh0(t0 + 3);
    BAR(); LGKM0(); MMA(0, 1); BAR();

    // ---- ph6: buf1 (mh1,nh0); stage B-lo(t0+3) [buf1 B died ph5]
    DS_A(BUFSZ, 1);
    if (more) IB(t0 + 3, 0);
    BAR(); LGKM0(); MMA(1, 0); BAR();

    // ---- ph7: buf1 (mh1,nh1); stage B-hi(t0+3); certify tile t0+2
    if (more) IB(t0 + 3, 2);
    BAR(); MMA(1, 1);
    if (more) { if constexpr (BM == 256) VM(6); else VM(4); } else { VM(0); }
    BAR();
  }

  // ---- epilogue. C/D map: col = lane&15, row = (lane>>4)*4 + reg
  const int c0 = bn0 + wc * 64 + lan15;
  if constexpr (OUTMODE == 0) {
    u16* C = (u16*)Cv;
    const int cb4 = (bn0 >> 8) * 4 + wc;  // partial-column index (0..127)
#pragma unroll
    for (int m = 0; m < MF; ++m)
#pragma unroll
      for (int r = 0; r < 4; ++r) {
        const int row = bm0 + wr * (BM / 2) + m * 16 + g * 4 + r;
        float part = 0.f;
#pragma unroll
        for (int n = 0; n < 4; ++n) {
          float v = __expf(acc[m][n][r] * scale);
          C[(size_t)row * ldc + c0 + n * 16] = f2bf(v);
          part += v;
        }
        part += __shfl_xor(part, 1, 64);
        part += __shfl_xor(part, 2, 64);
        part += __shfl_xor(part, 4, 64);
        part += __shfl_xor(part, 8, 64);
        if (lan15 == 0) partials[(size_t)row * 128 + cb4] = part;
      }
  } else {
    float* C = (float*)Cv;
#pragma unroll
    for (int m = 0; m < MF; ++m)
#pragma unroll
      for (int r = 0; r < 4; ++r) {
        const int row = bm0 + wr * (BM / 2) + m * 16 + g * 4 + r;
        const float iv = inv ? inv[row] : 1.0f;
#pragma unroll
        for (int n = 0; n < 4; ++n)
          C[(size_t)row * ldc + c0 + n * 16] = acc[m][n][r] * iv;
      }
  }
}

// ---------------- inv[row] = 1 / sum_j partials[row][j] --------------------
__global__ __launch_bounds__(256) void rowinv(const float* __restrict__ partials,
                                              float* __restrict__ inv) {
  const int row = blockIdx.x * 256 + threadIdx.x;
  const float4* p = (const float4*)(partials + (size_t)row * 128);
  float s = 0.f;
#pragma unroll
  for (int j = 0; j < 32; ++j) {
    float4 v = p[j];
    s += (v.x + v.y) + (v.z + v.w);
  }
  inv[row] = 1.0f / s;
}

// --------------- fallback: normalize E rows in place (bf16) ----------------
__global__ __launch_bounds__(256) void normalize_inplace(u16* __restrict__ E) {
  __shared__ float red[4];
  u16* row = E + (size_t)blockIdx.x * 8192;
  const int tid = threadIdx.x;
  float f[32];
  float s = 0.f;
#pragma unroll
  for (int c = 0; c < 4; ++c) {
    uint4 v = *((const uint4*)row + c * 256 + tid);
    unsigned u[4] = {v.x, v.y, v.z, v.w};
#pragma unroll
    for (int q = 0; q < 4; ++q) {
      f[c * 8 + q * 2] = bf2f((u16)(u[q] & 0xffffu));
      f[c * 8 + q * 2 + 1] = bf2f((u16)(u[q] >> 16));
      s += f[c * 8 + q * 2] + f[c * 8 + q * 2 + 1];
    }
  }
#pragma unroll
  for (int off = 32; off; off >>= 1) s += __shfl_xor(s, off, 64);
  if ((tid & 63) == 0) red[tid >> 6] = s;
  __syncthreads();
  const float iv = 1.0f / ((red[0] + red[1]) + (red[2] + red[3]));
#pragma unroll
  for (int c = 0; c < 4; ++c) {
    uint4 o;
    o.x = pack2(f[c * 8 + 0] * iv, f[c * 8 + 1] * iv);
    o.y = pack2(f[c * 8 + 2] * iv, f[c * 8 + 3] * iv);
    o.z = pack2(f[c * 8 + 4] * iv, f[c * 8 + 5] * iv);
    o.w = pack2(f[c * 8 + 6] * iv, f[c * 8 + 7] * iv);
    *((uint4*)row + c * 256 + tid) = o;
  }
}

// ---------------------------------------------------------------------------
extern "C" void kernel_launch(void* const* d_in, const int* in_sizes, int n_in,
                              void* d_out, int out_size, void* d_ws, size_t ws_size,
                              hipStream_t stream) {
  const float* Q = (const float*)d_in[0];
  const float* K = (const float*)d_in[1];
  const float* V = (const float*)d_in[2];

  char* ws = (char*)d_ws;
  u16* S = (u16*)ws;                                              // 128 MB
  u16* VT = (u16*)(ws + (size_t)134217728);                       // 16 MB
  float* partials = (float*)(ws + (size_t)134217728 + 16777216);  // 4 MB
  float* inv = (float*)(ws + (size_t)134217728 + 16777216 + 4194304);
  const bool haveInv =
      ws_size >= (size_t)134217728 + 16777216 + 4194304 + 32768;

  u16* Qb = (u16*)d_out;   // bf16 Q scratch (16 MB)
  u16* Kb = Qb + 8388608;  // bf16 K scratch (16 MB)

  cvt_bf16<<<4096, 256, 0, stream>>>(Q, Qb);
  cvt_bf16<<<4096, 256, 0, stream>>>(K, Kb);
  transpose_bf16<<<dim3(128, 16), 256, 0, stream>>>(V, VT);

  // E = exp(Q K^T / 32)  [8192 x 8192] bf16 ; grid 1024 (supertile decode)
  gemm8d<256, 0, 0><<<1024, 512, 0, stream>>>(
      Qb, Kb, S, nullptr, haveInv ? partials : (float*)(ws + 134217728 + 16777216),
      1024, 8192, 1.0f / 32.0f);

  if (haveInv) {
    rowinv<<<32, 256, 0, stream>>>(partials, inv);
    // O = diag(inv) E V  [8192 x 1024] f32 ; grid 256 (stripe-sharing decode)
    gemm8d<128, 1, 1><<<256, 512, 0, stream>>>(
        S, VT, d_out, inv, nullptr, 8192, 1024, 1.0f);
  } else {
    normalize_inplace<<<8192, 256, 0, stream>>>(S);
    gemm8d<128, 1, 1><<<256, 512, 0, stream>>>(
        S, VT, d_out, nullptr, nullptr, 8192, 1024, 1.0f);
  }
}

// Round 13
// 302.885 us; speedup vs baseline: 1.1081x; 1.0048x over previous
//
#include <hip/hip_runtime.h>
#include <hip/hip_bf16.h>

// ---------------------------------------------------------------------------
// attention via: E = exp(QK^T/32) (bf16), inv[r] = 1/sum_k E[r,k] (per-wave
// partials), O = diag(inv)*E*V.
// r13 = r12 (8-phase, 2-tile-ahead staging, counted VM(6)/VM(4) at ph3/ph7)
// with DE-PINNED sync primitives, matching the m201 template exactly:
//   BAR  = raw __builtin_amdgcn_s_barrier()          (no "memory" clobber)
//   WAITL= asm("s_waitcnt lgkmcnt(0)")               (no sched_barrier)
//   WAITV= asm("s_waitcnt vmcnt(n)")                 (no sched_barrier)
// Rationale (r12 cycle audit): phase time == LDS+MFMA serial sum (1433 cyc);
// the "memory"/sched_barrier(0) pins forbade the compiler from sinking MFMAs
// across barriers / hoisting next-phase ds_reads — the cross-phase overlap
// that gives m201 824 cyc/phase at identical geometry. Hazards stay safe:
// waitcnt instructions still execute in order (volatile), and ds_reads
// cannot cross may-aliasing global_load_lds calls.
// Staging death-windows, swizzle (0 conflicts), decodes, epilogues: r12,
// verified bit-exact (absmax 0.0004882812 expected unchanged).
// ws: [0,128MB)=E ; [128MB,144MB)=V^T ; [144MB,148MB)=partials ; then inv.
// ---------------------------------------------------------------------------

typedef __bf16 bf16x8 __attribute__((ext_vector_type(8)));
typedef float f32x4 __attribute__((ext_vector_type(4)));
typedef const __attribute__((address_space(1))) unsigned int* as1p;
typedef __attribute__((address_space(3))) unsigned int* as3p;
typedef unsigned short u16;

__device__ __forceinline__ u16 f2bf(float x) {
  unsigned u = __float_as_uint(x);
  u += 0x7fffu + ((u >> 16) & 1u);
  return (u16)(u >> 16);
}
__device__ __forceinline__ float bf2f(u16 b) { return __uint_as_float(((unsigned)b) << 16); }
__device__ __forceinline__ unsigned pack2(float lo, float hi) {
  return (unsigned)f2bf(lo) | ((unsigned)f2bf(hi) << 16);
}

#define BARX()   __builtin_amdgcn_s_barrier()
#define WAITL()  asm volatile("s_waitcnt lgkmcnt(0)")
#define WAITV(n) asm volatile("s_waitcnt vmcnt(" #n ")")

// --------------------------- f32 -> bf16 convert ---------------------------
__global__ __launch_bounds__(256) void cvt_bf16(const float* __restrict__ in,
                                                unsigned short* __restrict__ out) {
  const size_t i = (size_t)blockIdx.x * 256 + threadIdx.x;
  const float4* p = (const float4*)in + i * 2;
  float4 a = p[0], b = p[1];
  uint4 o;
  o.x = pack2(a.x, a.y);
  o.y = pack2(a.z, a.w);
  o.z = pack2(b.x, b.y);
  o.w = pack2(b.z, b.w);
  ((uint4*)out)[i] = o;
}

// ------------- V [8192,1024] f32 -> V^T [1024,8192] bf16 -------------------
__global__ __launch_bounds__(256) void transpose_bf16(const float* __restrict__ V,
                                                      unsigned short* __restrict__ VT) {
  __shared__ float t[64][65];
  const int rb = blockIdx.x * 64;
  const int cb = blockIdx.y * 64;
  const int tid = threadIdx.x;
#pragma unroll
  for (int it = 0; it < 4; ++it) {
    int r = it * 16 + (tid >> 4);
    int c = (tid & 15) * 4;
    float4 x = *(const float4*)(V + (size_t)(rb + r) * 1024 + cb + c);
    t[r][c] = x.x; t[r][c + 1] = x.y; t[r][c + 2] = x.z; t[r][c + 3] = x.w;
  }
  __syncthreads();
  const int j = tid & 63;
  const int c0 = (tid >> 6) * 16;
#pragma unroll
  for (int i = 0; i < 16; ++i) {
    int c = c0 + i;
    VT[(size_t)(cb + c) * 8192 + rb + j] = f2bf(t[j][c]);
  }
}

// -------------- 8-phase NT GEMM, 2-tile-ahead staging, de-pinned -----------
// C[M,N](ldc) = A[M,K]*B[N,K]^T, BN=256. 512 threads, 8 waves (2M x 4N).
// DEC 0: grid 1024 = supertile 16bm x 8bn per XCD chunk   [GEMM1]
// DEC 1: grid 256  = 8bm x 4bn per XCD chunk (bn fastest) [GEMM2]
// OUTMODE 0: C=bf16 exp(acc*scale) + per-wave row partials.
// OUTMODE 1: C=f32 acc*inv[row].
template <int BM, int OUTMODE, int DEC>
__global__ __launch_bounds__(512, 2) void gemm8d(const u16* __restrict__ A,
                                                 const u16* __restrict__ B,
                                                 void* __restrict__ Cv,
                                                 const float* __restrict__ inv,
                                                 float* __restrict__ partials,
                                                 int K, int ldc, float scale) {
  constexpr int MF = BM / 32;       // per-wave m-frags (8 or 4)
  constexpr int MH = MF / 2;        // m-frags per half
  constexpr int ABUF = BM * 128;
  constexpr int BBUF = 32768;
  constexpr int BUFSZ = ABUF + BBUF;
  __shared__ __align__(1024) char smem[2 * BUFSZ];

  const int tid = threadIdx.x;
  const int lane = tid & 63, wave = tid >> 6;
  const int wr = wave >> 2, wc = wave & 3;
  const int lan15 = lane & 15, g = lane >> 4, l7 = lane & 7;

  // T1: bijective XCD swizzle (nwg % 8 == 0 at both call sites)
  const int nwg = gridDim.x;
  const int wg = (blockIdx.x & 7) * (nwg >> 3) + (blockIdx.x >> 3);
  int bm0, bn0;
  if constexpr (DEC == 0) {
    const int r = wg & 255;
    bm0 = (r >> 3) * 256;
    bn0 = (((wg >> 8) << 3) | (r & 7)) * 256;
  } else {
    // 256 wgs: XCD chunk of 32 = 8 bm x 4 bn, bn fastest -> the 4 blocks
    // sharing an S-row-stripe sit on ONE XCD (L2 serves 3 of 4 reads).
    const int chunk = wg >> 5;
    const int within = wg & 31;
    bm0 = (chunk * 8 + (within >> 2)) * BM;
    bn0 = (within & 3) * 256;
  }

  // staging: thread -> row (tid>>3), swizzled src col-block (tid&7)^(row&7)
  const int sr = tid >> 3;
  const int scb = ((tid & 7) ^ (sr & 7)) * 8;
  const u16* Ags = A + (size_t)(bm0 + sr) * K + scb;
  const u16* Bgs = B + (size_t)(bn0 + sr) * K + scb;

  // fragment-read swizzled 16B-slot offsets
  const int sa0 = ((0 + g) ^ l7) * 16;
  const int sa1 = ((4 + g) ^ l7) * 16;
  const int abase = (wr * (BM / 2) + lan15) * 128;
  const int bbase = ABUF + (wc * 64 + lan15) * 128;

  f32x4 acc[MF][4];
#pragma unroll
  for (int m = 0; m < MF; ++m)
#pragma unroll
    for (int n = 0; n < 4; ++n) acc[m][n] = f32x4{0.f, 0.f, 0.f, 0.f};

  const int nt = K >> 6;
  const int niter = nt >> 1;

  // stage units: 2 x global_load_lds each, explicit j-batches (64 rows each)
  auto IA = [&](int t, int ja, int jb) {
    char* bb = smem + (t & 1) * BUFSZ;
    const size_t ko = (size_t)t * 64;
    __builtin_amdgcn_global_load_lds((as1p)(Ags + (size_t)ja * 64 * K + ko),
                                     (as3p)(bb + ja * 8192 + tid * 16), 16, 0, 0);
    __builtin_amdgcn_global_load_lds((as1p)(Ags + (size_t)jb * 64 * K + ko),
                                     (as3p)(bb + jb * 8192 + tid * 16), 16, 0, 0);
  };
  auto IB = [&](int t, int j0) {  // batches j0, j0+1
    char* bb = smem + (t & 1) * BUFSZ + ABUF;
    const size_t ko = (size_t)t * 64;
    __builtin_amdgcn_global_load_lds((as1p)(Bgs + (size_t)j0 * 64 * K + ko),
                                     (as3p)(bb + j0 * 8192 + tid * 16), 16, 0, 0);
    __builtin_amdgcn_global_load_lds((as1p)(Bgs + (size_t)(j0 + 1) * 64 * K + ko),
                                     (as3p)(bb + (j0 + 1) * 8192 + tid * 16), 16, 0, 0);
  };
  auto IA_mh0 = [&](int t) { if constexpr (BM == 256) IA(t, 0, 2); };
  auto IA_mh1 = [&](int t) { if constexpr (BM == 256) IA(t, 1, 3); else IA(t, 0, 1); };

  bf16x8 a[MH][2], b[4][2];
  auto DS_A = [&](int bb, int mh) {
#pragma unroll
    for (int m = 0; m < MH; ++m) {
      a[m][0] = *(const bf16x8*)(smem + bb + abase + (mh * MH + m) * 2048 + sa0);
      a[m][1] = *(const bf16x8*)(smem + bb + abase + (mh * MH + m) * 2048 + sa1);
    }
  };
  auto DS_B = [&](int bb, int nh) {
#pragma unroll
    for (int n = 0; n < 2; ++n) {
      b[nh * 2 + n][0] = *(const bf16x8*)(smem + bb + bbase + (nh * 2 + n) * 2048 + sa0);
      b[nh * 2 + n][1] = *(const bf16x8*)(smem + bb + bbase + (nh * 2 + n) * 2048 + sa1);
    }
  };
  auto MMA = [&](int mh, int nh) {
    __builtin_amdgcn_s_setprio(1);
#pragma unroll
    for (int m = 0; m < MH; ++m)
#pragma unroll
      for (int n = 0; n < 2; ++n)
#pragma unroll
        for (int ks = 0; ks < 2; ++ks)
          acc[mh * MH + m][nh * 2 + n] = __builtin_amdgcn_mfma_f32_16x16x32_bf16(
              a[m][ks], b[nh * 2 + n][ks], acc[mh * MH + m][nh * 2 + n], 0, 0, 0);
    __builtin_amdgcn_s_setprio(0);
  };

  // ---- prologue: tile0 fully + tile1 {A-mh0, B}; force tile0 landed.
  if constexpr (BM == 256) {
    IA(0, 0, 2); IB(0, 0); IB(0, 2); IA(0, 1, 3);
    IA(1, 0, 2); IB(1, 0); IB(1, 2);
    WAITV(6);
  } else {
    IB(0, 0); IB(0, 2); IA(0, 0, 1);
    IB(1, 0); IB(1, 2);
    WAITV(4);
  }
  BARX();

  for (int i = 0; i < niter; ++i) {
    const int t0 = 2 * i;
    const bool more = (i + 1 < niter);

    // ---- ph0: buf0 (mh0,nh0); stage A-mh1(t0+1)
    DS_A(0, 0); DS_B(0, 0);
    IA_mh1(t0 + 1);
    BARX(); WAITL(); MMA(0, 0); BARX();

    // ---- ph1: buf0 (mh0,nh1); stage A-mh0(t0+2)
    DS_B(0, 1);
    if (more) IA_mh0(t0 + 2);
    BARX(); WAITL(); MMA(0, 1); BARX();

    // ---- ph2: buf0 (mh1,nh0); stage B-lo(t0+2)
    DS_A(0, 1);
    if (more) IB(t0 + 2, 0);
    BARX(); WAITL(); MMA(1, 0); BARX();

    // ---- ph3: buf0 (mh1,nh1); stage B-hi(t0+2); certify tile t0+1
    if (more) IB(t0 + 2, 2);
    BARX(); MMA(1, 1);
    if (more) { if constexpr (BM == 256) WAITV(6); else WAITV(4); } else { WAITV(0); }
    BARX();

    // ---- ph4: buf1 (mh0,nh0); stage A-mh1(t0+2)
    DS_A(BUFSZ, 0); DS_B(BUFSZ, 0);
    if (more) IA_mh1(t0 + 2);
    BARX(); WAITL(); MMA(0, 0); BARX();

    // ---- ph5: buf1 (mh0,nh1); stage A-mh0(t0+3)
    DS_B(BUFSZ, 1);
    if (more) IA_mh0(t0 + 3);
    BARX(); WAITL(); MMA(0, 1); BARX();

    // ---- ph6: buf1 (mh1,nh0); stage B-lo(t0+3)
    DS_A(BUFSZ, 1);
    if (more) IB(t0 + 3, 0);
    BARX(); WAITL(); MMA(1, 0); BARX();

    // ---- ph7: buf1 (mh1,nh1); stage B-hi(t0+3); certify tile t0+2
    if (more) IB(t0 + 3, 2);
    BARX(); MMA(1, 1);
    if (more) { if constexpr (BM == 256) WAITV(6); else WAITV(4); } else { WAITV(0); }
    BARX();
  }

  // ---- epilogue. C/D map: col = lane&15, row = (lane>>4)*4 + reg
  const int c0 = bn0 + wc * 64 + lan15;
  if constexpr (OUTMODE == 0) {
    u16* C = (u16*)Cv;
    const int cb4 = (bn0 >> 8) * 4 + wc;  // partial-column index (0..127)
#pragma unroll
    for (int m = 0; m < MF; ++m)
#pragma unroll
      for (int r = 0; r < 4; ++r) {
        const int row = bm0 + wr * (BM / 2) + m * 16 + g * 4 + r;
        float part = 0.f;
#pragma unroll
        for (int n = 0; n < 4; ++n) {
          float v = __expf(acc[m][n][r] * scale);
          C[(size_t)row * ldc + c0 + n * 16] = f2bf(v);
          part += v;
        }
        part += __shfl_xor(part, 1, 64);
        part += __shfl_xor(part, 2, 64);
        part += __shfl_xor(part, 4, 64);
        part += __shfl_xor(part, 8, 64);
        if (lan15 == 0) partials[(size_t)row * 128 + cb4] = part;
      }
  } else {
    float* C = (float*)Cv;
#pragma unroll
    for (int m = 0; m < MF; ++m)
#pragma unroll
      for (int r = 0; r < 4; ++r) {
        const int row = bm0 + wr * (BM / 2) + m * 16 + g * 4 + r;
        const float iv = inv ? inv[row] : 1.0f;
#pragma unroll
        for (int n = 0; n < 4; ++n)
          C[(size_t)row * ldc + c0 + n * 16] = acc[m][n][r] * iv;
      }
  }
}

// ---------------- inv[row] = 1 / sum_j partials[row][j] --------------------
__global__ __launch_bounds__(256) void rowinv(const float* __restrict__ partials,
                                              float* __restrict__ inv) {
  const int row = blockIdx.x * 256 + threadIdx.x;
  const float4* p = (const float4*)(partials + (size_t)row * 128);
  float s = 0.f;
#pragma unroll
  for (int j = 0; j < 32; ++j) {
    float4 v = p[j];
    s += (v.x + v.y) + (v.z + v.w);
  }
  inv[row] = 1.0f / s;
}

// --------------- fallback: normalize E rows in place (bf16) ----------------
__global__ __launch_bounds__(256) void normalize_inplace(u16* __restrict__ E) {
  __shared__ float red[4];
  u16* row = E + (size_t)blockIdx.x * 8192;
  const int tid = threadIdx.x;
  float f[32];
  float s = 0.f;
#pragma unroll
  for (int c = 0; c < 4; ++c) {
    uint4 v = *((const uint4*)row + c * 256 + tid);
    unsigned u[4] = {v.x, v.y, v.z, v.w};
#pragma unroll
    for (int q = 0; q < 4; ++q) {
      f[c * 8 + q * 2] = bf2f((u16)(u[q] & 0xffffu));
      f[c * 8 + q * 2 + 1] = bf2f((u16)(u[q] >> 16));
      s += f[c * 8 + q * 2] + f[c * 8 + q * 2 + 1];
    }
  }
#pragma unroll
  for (int off = 32; off; off >>= 1) s += __shfl_xor(s, off, 64);
  if ((tid & 63) == 0) red[tid >> 6] = s;
  __syncthreads();
  const float iv = 1.0f / ((red[0] + red[1]) + (red[2] + red[3]));
#pragma unroll
  for (int c = 0; c < 4; ++c) {
    uint4 o;
    o.x = pack2(f[c * 8 + 0] * iv, f[c * 8 + 1] * iv);
    o.y = pack2(f[c * 8 + 2] * iv, f[c * 8 + 3] * iv);
    o.z = pack2(f[c * 8 + 4] * iv, f[c * 8 + 5] * iv);
    o.w = pack2(f[c * 8 + 6] * iv, f[c * 8 + 7] * iv);
    *((uint4*)row + c * 256 + tid) = o;
  }
}

// ---------------------------------------------------------------------------
extern "C" void kernel_launch(void* const* d_in, const int* in_sizes, int n_in,
                              void* d_out, int out_size, void* d_ws, size_t ws_size,
                              hipStream_t stream) {
  const float* Q = (const float*)d_in[0];
  const float* K = (const float*)d_in[1];
  const float* V = (const float*)d_in[2];

  char* ws = (char*)d_ws;
  u16* S = (u16*)ws;                                              // 128 MB
  u16* VT = (u16*)(ws + (size_t)134217728);                       // 16 MB
  float* partials = (float*)(ws + (size_t)134217728 + 16777216);  // 4 MB
  float* inv = (float*)(ws + (size_t)134217728 + 16777216 + 4194304);
  const bool haveInv =
      ws_size >= (size_t)134217728 + 16777216 + 4194304 + 32768;

  u16* Qb = (u16*)d_out;   // bf16 Q scratch (16 MB)
  u16* Kb = Qb + 8388608;  // bf16 K scratch (16 MB)

  cvt_bf16<<<4096, 256, 0, stream>>>(Q, Qb);
  cvt_bf16<<<4096, 256, 0, stream>>>(K, Kb);
  transpose_bf16<<<dim3(128, 16), 256, 0, stream>>>(V, VT);

  // E = exp(Q K^T / 32)  [8192 x 8192] bf16 ; grid 1024 (supertile decode)
  gemm8d<256, 0, 0><<<1024, 512, 0, stream>>>(
      Qb, Kb, S, nullptr, haveInv ? partials : (float*)(ws + 134217728 + 16777216),
      1024, 8192, 1.0f / 32.0f);

  if (haveInv) {
    rowinv<<<32, 256, 0, stream>>>(partials, inv);
    // O = diag(inv) E V  [8192 x 1024] f32 ; grid 256 (stripe-sharing decode)
    gemm8d<128, 1, 1><<<256, 512, 0, stream>>>(
        S, VT, d_out, inv, nullptr, 8192, 1024, 1.0f);
  } else {
    normalize_inplace<<<8192, 256, 0, stream>>>(S);
    gemm8d<128, 1, 1><<<256, 512, 0, stream>>>(
        S, VT, d_out, nullptr, nullptr, 8192, 1024, 1.0f);
  }
}